// Round 5
// baseline (422.778 us; speedup 1.0000x reference)
//
#include <hip/hip_runtime.h>
#include <hip/hip_bf16.h>
#include <cstdint>

#define B_DIM 8192
#define D_DIM 512
#define BM 128
#define BN 128
#define BK 32
#define NPANEL 8                 // col panels per block
#define BLK_COLS (BN * NPANEL)   // 1024
#define NPART 16                 // 8 col-octants x 2 wc-halves

typedef __attribute__((ext_vector_type(8))) short bf16x8;
typedef __attribute__((ext_vector_type(4))) float f32x4;

typedef __attribute__((address_space(1))) const void* gas_ptr;
typedef __attribute__((address_space(3))) void* las_ptr;

static __device__ __forceinline__ unsigned short f2bf(float x) {
    __hip_bfloat16 h = __float2bfloat16(x);
    return *reinterpret_cast<unsigned short*>(&h);
}

// One wave per row: L2-normalize (f32) and emit bf16.
__global__ __launch_bounds__(256) void normalize_rows(
    const float* __restrict__ V, const float* __restrict__ T,
    unsigned short* __restrict__ Vn, unsigned short* __restrict__ Tn)
{
    const int wave = threadIdx.x >> 6;
    const int lane = threadIdx.x & 63;
    const int row = blockIdx.x * 4 + wave;     // 0..16383 (V rows then T rows)
    const float* src;
    unsigned short* dst;
    if (row < B_DIM) {
        src = V + (size_t)row * D_DIM;
        dst = Vn + (size_t)row * D_DIM;
    } else {
        src = T + (size_t)(row - B_DIM) * D_DIM;
        dst = Tn + (size_t)(row - B_DIM) * D_DIM;
    }
    float4 a = *(const float4*)(src + lane * 4);
    float4 b = *(const float4*)(src + 256 + lane * 4);
    float ss = a.x*a.x + a.y*a.y + a.z*a.z + a.w*a.w
             + b.x*b.x + b.y*b.y + b.z*b.z + b.w*b.w;
    #pragma unroll
    for (int off = 32; off; off >>= 1) ss += __shfl_xor(ss, off);
    const float inv = 1.0f / fmaxf(sqrtf(ss), 1e-12f);
    ushort4 oa, ob;
    oa.x = f2bf(a.x * inv); oa.y = f2bf(a.y * inv);
    oa.z = f2bf(a.z * inv); oa.w = f2bf(a.w * inv);
    ob.x = f2bf(b.x * inv); ob.y = f2bf(b.y * inv);
    ob.z = f2bf(b.z * inv); ob.w = f2bf(b.w * inv);
    *(ushort4*)(dst + lane * 4) = oa;
    *(ushort4*)(dst + 256 + lane * 4) = ob;
}

// Block = 128 rows x 1024 cols (8 panels walked left->right).
// Per panel: m97-structure K-loop (BK=32, global_load_lds w16) + vectorized
// epilogue. Row-sums accumulate in registers across panels; one plain store
// per (row, co, wc) into part[16][8192] — no atomics anywhere.
__global__ __launch_bounds__(256) void gemm_fused(
    const unsigned short* __restrict__ Vn, const unsigned short* __restrict__ Tn,
    const int* __restrict__ noisy,
    float* __restrict__ sim_out, float* __restrict__ mask_out,
    float* __restrict__ part)
{
    __shared__ unsigned short Al[BM * BK];   // [128][32] bf16, linear
    __shared__ unsigned short Bl[BN * BK];

    const int tid  = threadIdx.x;
    const int wave = tid >> 6;
    const int lane = tid & 63;
    const int wr = wave >> 1;       // wave row (0..1)
    const int wc = wave & 1;        // wave col (0..1)

    // 512 blocks = 64 row-panels x 8 col-octants.
    // xcd = bid&7 owns row band [xcd*8, xcd*8+8) (A-slice 1MB, L2-resident).
    const int bid = blockIdx.x;
    const int xcd = bid & 7;
    const int j   = bid >> 3;          // 0..63
    const int rp  = j & 7;             // row panel within band
    const int co  = j >> 3;            // col octant 0..7
    const int brow = (xcd * 8 + rp) * BM;
    const int col0 = co * BLK_COLS;

    const int sr = lane >> 2;          // staging row within 16-row chunk
    const int sc = (lane & 3) * 8;     // staging col (bf16 elems)
    const int c0 = wave * 2;

    const int fr = lane & 15;
    const int ko = (lane >> 4) * 8;

    const float Tinv = 1.0f / 0.07f;
    const int ci = lane & 15;           // sim row within 16-block
    const int cg = lane >> 4;           // sim col group (4 cols each)

    float rowacc[4] = {0.0f, 0.0f, 0.0f, 0.0f};
    int rn[4];
    #pragma unroll
    for (int m = 0; m < 4; ++m)
        rn[m] = noisy[brow + wr * 64 + m * 16 + ci];

    for (int p = 0; p < NPANEL; ++p) {
        const int bcol = col0 + p * BN;
        f32x4 acc[4][4] = {};           // sim^T fragments for this panel

        for (int k0 = 0; k0 < D_DIM; k0 += BK) {
            #pragma unroll
            for (int q = 0; q < 2; ++q) {
                const int cw  = c0 + q;
                const int row = cw * 16 + sr;
                const unsigned short* ga = Vn + (size_t)(brow + row) * D_DIM + k0 + sc;
                const unsigned short* gb = Tn + (size_t)(bcol + row) * D_DIM + k0 + sc;
                __builtin_amdgcn_global_load_lds((gas_ptr)ga, (las_ptr)&Al[cw * 512], 16, 0, 0);
                __builtin_amdgcn_global_load_lds((gas_ptr)gb, (las_ptr)&Bl[cw * 512], 16, 0, 0);
            }
            __syncthreads();

            bf16x8 af[4], bfr[4];
            #pragma unroll
            for (int m = 0; m < 4; ++m)
                af[m] = *(const bf16x8*)&Al[(wr * 64 + m * 16 + fr) * BK + ko];
            #pragma unroll
            for (int n = 0; n < 4; ++n)
                bfr[n] = *(const bf16x8*)&Bl[(wc * 64 + n * 16 + fr) * BK + ko];

            // swapped operands: lane holds sim[m*16+(lane&15)][n*16+(lane>>4)*4+r]
            #pragma unroll
            for (int m = 0; m < 4; ++m)
                #pragma unroll
                for (int n = 0; n < 4; ++n)
                    acc[m][n] = __builtin_amdgcn_mfma_f32_16x16x32_bf16(
                        bfr[n], af[m], acc[m][n], 0, 0, 0);
            __syncthreads();
        }

        // ---- fused epilogue for this panel ----
        int4 cn4[4];
        #pragma unroll
        for (int n = 0; n < 4; ++n)
            cn4[n] = *(const int4*)&noisy[bcol + wc * 64 + n * 16 + cg * 4];

        #pragma unroll
        for (int m = 0; m < 4; ++m) {
            const int grow = brow + wr * 64 + m * 16 + ci;
            const size_t rowoff = (size_t)grow * B_DIM;
            float partial = 0.0f;
            #pragma unroll
            for (int n = 0; n < 4; ++n) {
                const int colbase = bcol + wc * 64 + n * 16 + cg * 4;
                const f32x4 s = acc[m][n];
                f32x4 mk;
                mk[0] = (rn[m] | cn4[n].x) ? 1.0f : 0.0f;
                mk[1] = (rn[m] | cn4[n].y) ? 1.0f : 0.0f;
                mk[2] = (rn[m] | cn4[n].z) ? 1.0f : 0.0f;
                mk[3] = (rn[m] | cn4[n].w) ? 1.0f : 0.0f;
                *(f32x4*)(sim_out  + rowoff + colbase) = s;
                *(f32x4*)(mask_out + rowoff + colbase) = mk;
                partial += __expf(s[0] * Tinv) * mk[0];
                partial += __expf(s[1] * Tinv) * mk[1];
                partial += __expf(s[2] * Tinv) * mk[2];
                partial += __expf(s[3] * Tinv) * mk[3];
            }
            rowacc[m] += partial;
        }
        __syncthreads();   // protect LDS reuse across panels
    }

    // one plain store per (row, co, wc): part[co*2+wc][grow].
    // wc=0 and wc=1 waves cover different col halves of the SAME rows ->
    // they MUST have distinct slots (R4 bug: shared slot lost half the sum).
    #pragma unroll
    for (int m = 0; m < 4; ++m) {
        float v = rowacc[m];
        v += __shfl_xor(v, 16);
        v += __shfl_xor(v, 32);
        if (lane < 16) {
            const int grow = brow + wr * 64 + m * 16 + ci;
            part[(size_t)(co * 2 + wc) * B_DIM + grow] = v;
        }
    }
}

// stage 1: 32 blocks x 256 rows -> per-block sum of log(rowsum+eps)
__global__ __launch_bounds__(256) void loss_stage1(
    const float* __restrict__ part, float* __restrict__ s1)
{
    __shared__ float wsum[4];
    const int row = blockIdx.x * 256 + threadIdx.x;
    float s = 0.0f;
    #pragma unroll
    for (int c = 0; c < NPART; ++c)
        s += part[(size_t)c * B_DIM + row];
    float l = logf(s + 1e-8f);
    #pragma unroll
    for (int off = 32; off; off >>= 1) l += __shfl_xor(l, off);
    if ((threadIdx.x & 63) == 0) wsum[threadIdx.x >> 6] = l;
    __syncthreads();
    if (threadIdx.x == 0)
        s1[blockIdx.x] = (wsum[0] + wsum[1]) + (wsum[2] + wsum[3]);
}

// stage 2: single wave sums the 32 block partials
__global__ __launch_bounds__(64) void loss_stage2(
    const float* __restrict__ s1, float* __restrict__ out)
{
    const int lane = threadIdx.x;
    float s = (lane < 32) ? s1[lane] : 0.0f;
    #pragma unroll
    for (int off = 32; off; off >>= 1) s += __shfl_xor(s, off);
    if (lane == 0) {
        const float loss = s * (1.0f / (float)B_DIM);
        out[0] = loss;   // complementary_loss
        out[1] = loss;   // brownian_loss (identical chain)
    }
}

extern "C" void kernel_launch(void* const* d_in, const int* in_sizes, int n_in,
                              void* d_out, int out_size, void* d_ws, size_t ws_size,
                              hipStream_t stream) {
    const float* V = (const float*)d_in[0];
    const float* T = (const float*)d_in[1];
    const int* noisy = (const int*)d_in[3];   // confident_clean_mask (d_in[2]) unused
    float* out = (float*)d_out;

    float* mask_out = out + 2;
    float* sim_out  = out + 2 + (size_t)B_DIM * B_DIM;

    unsigned short* Vn = (unsigned short*)d_ws;                       // 8 MB
    unsigned short* Tn = Vn + (size_t)B_DIM * D_DIM;                  // 8 MB
    float* part = (float*)(Tn + (size_t)B_DIM * D_DIM);               // 512 KB
    float* s1   = part + (size_t)NPART * B_DIM;                       // 128 B

    normalize_rows<<<(2 * B_DIM) / 4, 256, 0, stream>>>(V, T, Vn, Tn);
    gemm_fused<<<512, 256, 0, stream>>>(Vn, Tn, noisy, sim_out, mask_out, part);
    loss_stage1<<<32, 256, 0, stream>>>(part, s1);
    loss_stage2<<<1, 64, 0, stream>>>(s1, out);
}

// Round 6
// 274.046 us; speedup vs baseline: 1.5427x; 1.5427x over previous
//
#include <hip/hip_runtime.h>
#include <hip/hip_bf16.h>
#include <cstdint>

#define B_DIM 8192
#define D_DIM 512
#define BM 128
#define BN 128
#define BK 32
#define KSTEPS (D_DIM / BK)   // 16

typedef __attribute__((ext_vector_type(8))) short bf16x8;
typedef __attribute__((ext_vector_type(4))) float f32x4;

typedef __attribute__((address_space(1))) const void* gas_ptr;
typedef __attribute__((address_space(3))) void* las_ptr;

static __device__ __forceinline__ unsigned short f2bf(float x) {
    __hip_bfloat16 h = __float2bfloat16(x);
    return *reinterpret_cast<unsigned short*>(&h);
}

// One wave per row: L2-normalize (f32) and emit bf16.
__global__ __launch_bounds__(256) void normalize_rows(
    const float* __restrict__ V, const float* __restrict__ T,
    unsigned short* __restrict__ Vn, unsigned short* __restrict__ Tn)
{
    const int wave = threadIdx.x >> 6;
    const int lane = threadIdx.x & 63;
    const int row = blockIdx.x * 4 + wave;     // 0..16383 (V rows then T rows)
    const float* src;
    unsigned short* dst;
    if (row < B_DIM) {
        src = V + (size_t)row * D_DIM;
        dst = Vn + (size_t)row * D_DIM;
    } else {
        src = T + (size_t)(row - B_DIM) * D_DIM;
        dst = Tn + (size_t)(row - B_DIM) * D_DIM;
    }
    float4 a = *(const float4*)(src + lane * 4);
    float4 b = *(const float4*)(src + 256 + lane * 4);
    float ss = a.x*a.x + a.y*a.y + a.z*a.z + a.w*a.w
             + b.x*b.x + b.y*b.y + b.z*b.z + b.w*b.w;
    #pragma unroll
    for (int off = 32; off; off >>= 1) ss += __shfl_xor(ss, off);
    const float inv = 1.0f / fmaxf(sqrtf(ss), 1e-12f);
    ushort4 oa, ob;
    oa.x = f2bf(a.x * inv); oa.y = f2bf(a.y * inv);
    oa.z = f2bf(a.z * inv); oa.w = f2bf(a.w * inv);
    ob.x = f2bf(b.x * inv); ob.y = f2bf(b.y * inv);
    ob.z = f2bf(b.z * inv); ob.w = f2bf(b.w * inv);
    *(ushort4*)(dst + lane * 4) = oa;
    *(ushort4*)(dst + 256 + lane * 4) = ob;
}

// R3 structure (4096 blocks, 128x128 tile, XCD-band col-panel-major mapping,
// single end-of-kernel epilogue + atomic rowsum) + double-buffered 2-phase
// K-loop: STAGE(next) issued BEFORE ds_read/MFMA(cur), one barrier per step.
__global__ __launch_bounds__(256, 4) void gemm_fused(
    const unsigned short* __restrict__ Vn, const unsigned short* __restrict__ Tn,
    const int* __restrict__ noisy,
    float* __restrict__ sim_out, float* __restrict__ mask_out,
    float* __restrict__ rowsum)
{
    __shared__ unsigned short Al[2][BM * BK];   // 2 x 8 KB
    __shared__ unsigned short Bl[2][BN * BK];   // 2 x 8 KB

    const int tid  = threadIdx.x;
    const int wave = tid >> 6;
    const int lane = tid & 63;
    const int wr = wave >> 1;       // wave row (0..1)
    const int wc = wave & 1;        // wave col (0..1)

    // XCD-band mapping (R3, proven FETCH win): xcd = bid&7 owns row band
    // [xcd*8, xcd*8+8) panels; column-panel-major within the band.
    const int bid = blockIdx.x;
    const int xcd = bid & 7;
    const int i   = bid >> 3;          // 0..511
    const int cp  = i >> 3;            // col panel 0..63 (slow)
    const int rp  = i & 7;             // row panel within band (fast)
    const int brow = (xcd * 8 + rp) * BM;
    const int bcol = cp * BN;

    // staging: each wave issues 2 x global_load_lds(16B) per matrix per K-step
    const int sr = lane >> 2;          // row within a 16-row chunk
    const int sc = (lane & 3) * 8;     // col (bf16 elements)
    const int c0 = wave * 2;

    const int fr = lane & 15;
    const int ko = (lane >> 4) * 8;

#define STAGE(buf, k0) do {                                                        \
        _Pragma("unroll")                                                          \
        for (int q = 0; q < 2; ++q) {                                              \
            const int cw  = c0 + q;                                                \
            const int row = cw * 16 + sr;                                          \
            const unsigned short* ga = Vn + (size_t)(brow + row) * D_DIM + (k0) + sc; \
            const unsigned short* gb = Tn + (size_t)(bcol + row) * D_DIM + (k0) + sc; \
            __builtin_amdgcn_global_load_lds((gas_ptr)ga, (las_ptr)&Al[buf][cw * 512], 16, 0, 0); \
            __builtin_amdgcn_global_load_lds((gas_ptr)gb, (las_ptr)&Bl[buf][cw * 512], 16, 0, 0); \
        }                                                                          \
    } while (0)

    f32x4 acc[4][4] = {};              // sim^T fragments

    STAGE(0, 0);
    __syncthreads();                   // buf0 staged (vmcnt(0) drained per-wave)

    for (int t = 0; t < KSTEPS; ++t) {
        const int cur = t & 1;
        if (t < KSTEPS - 1)
            STAGE(cur ^ 1, (t + 1) * BK);   // prefetch next tile (async, in flight
                                            // during ds_read + MFMA below)
        bf16x8 af[4], bfr[4];
        #pragma unroll
        for (int m = 0; m < 4; ++m)
            af[m] = *(const bf16x8*)&Al[cur][(wr * 64 + m * 16 + fr) * BK + ko];
        #pragma unroll
        for (int n = 0; n < 4; ++n)
            bfr[n] = *(const bf16x8*)&Bl[cur][(wc * 64 + n * 16 + fr) * BK + ko];

        // swapped operands: lane holds sim[m*16+(lane&15)][n*16+(lane>>4)*4+r]
        #pragma unroll
        for (int m = 0; m < 4; ++m)
            #pragma unroll
            for (int n = 0; n < 4; ++n)
                acc[m][n] = __builtin_amdgcn_mfma_f32_16x16x32_bf16(
                    bfr[n], af[m], acc[m][n], 0, 0, 0);

        __syncthreads();   // one barrier/step: drains prefetch (vmcnt) and
                           // guarantees all ds_reads of buf[cur] are done
                           // before it is restaged at t+2.
    }
#undef STAGE

    // ---- fused epilogue (vectorized, cached stores; drains at wave exit) ----
    const float Tinv = 1.0f / 0.07f;
    const int ci = lane & 15;           // sim row within 16-block
    const int cg = lane >> 4;           // sim col group (4 cols each)

    int rn[4];
    #pragma unroll
    for (int m = 0; m < 4; ++m)
        rn[m] = noisy[brow + wr * 64 + m * 16 + ci];

    int4 cn4[4];
    #pragma unroll
    for (int n = 0; n < 4; ++n)
        cn4[n] = *(const int4*)&noisy[bcol + wc * 64 + n * 16 + cg * 4];

    #pragma unroll
    for (int m = 0; m < 4; ++m) {
        const int grow = brow + wr * 64 + m * 16 + ci;
        const size_t rowoff = (size_t)grow * B_DIM;
        float partial = 0.0f;
        #pragma unroll
        for (int n = 0; n < 4; ++n) {
            const int colbase = bcol + wc * 64 + n * 16 + cg * 4;
            const f32x4 s = acc[m][n];
            f32x4 mk;
            mk[0] = (rn[m] | cn4[n].x) ? 1.0f : 0.0f;
            mk[1] = (rn[m] | cn4[n].y) ? 1.0f : 0.0f;
            mk[2] = (rn[m] | cn4[n].z) ? 1.0f : 0.0f;
            mk[3] = (rn[m] | cn4[n].w) ? 1.0f : 0.0f;
            *(f32x4*)(sim_out  + rowoff + colbase) = s;
            *(f32x4*)(mask_out + rowoff + colbase) = mk;
            partial += __expf(s[0] * Tinv) * mk[0];
            partial += __expf(s[1] * Tinv) * mk[1];
            partial += __expf(s[2] * Tinv) * mk[2];
            partial += __expf(s[3] * Tinv) * mk[3];
        }
        // lanes {ci, ci+16, ci+32, ci+48} hold the same sim row
        partial += __shfl_xor(partial, 16);
        partial += __shfl_xor(partial, 32);
        if (lane < 16) atomicAdd(&rowsum[grow], partial);
    }
}

__global__ __launch_bounds__(256) void loss_reduce(
    const float* __restrict__ rowsum, float* __restrict__ out)
{
    __shared__ float wsum[4];
    float s = 0.0f;
    for (int i = threadIdx.x; i < B_DIM; i += 256)
        s += logf(rowsum[i] + 1e-8f);
    #pragma unroll
    for (int off = 32; off; off >>= 1) s += __shfl_xor(s, off);
    if ((threadIdx.x & 63) == 0) wsum[threadIdx.x >> 6] = s;
    __syncthreads();
    if (threadIdx.x == 0) {
        const float t = (wsum[0] + wsum[1]) + (wsum[2] + wsum[3]);
        const float loss = t * (1.0f / (float)B_DIM);
        out[0] = loss;   // complementary_loss
        out[1] = loss;   // brownian_loss (identical chain)
    }
}

extern "C" void kernel_launch(void* const* d_in, const int* in_sizes, int n_in,
                              void* d_out, int out_size, void* d_ws, size_t ws_size,
                              hipStream_t stream) {
    const float* V = (const float*)d_in[0];
    const float* T = (const float*)d_in[1];
    const int* noisy = (const int*)d_in[3];   // confident_clean_mask (d_in[2]) unused
    float* out = (float*)d_out;

    float* mask_out = out + 2;
    float* sim_out  = out + 2 + (size_t)B_DIM * B_DIM;

    unsigned short* Vn = (unsigned short*)d_ws;                       // 8 MB
    unsigned short* Tn = Vn + (size_t)B_DIM * D_DIM;                  // 8 MB
    float* rowsum = (float*)(Tn + (size_t)B_DIM * D_DIM);             // 32 KB

    hipMemsetAsync(rowsum, 0, B_DIM * sizeof(float), stream);
    normalize_rows<<<(2 * B_DIM) / 4, 256, 0, stream>>>(V, T, Vn, Tn);
    gemm_fused<<<64 * 64, 256, 0, stream>>>(Vn, Tn, noisy, sim_out, mask_out, rowsum);
    loss_reduce<<<1, 256, 0, stream>>>(rowsum, out);
}

// Round 7
// 255.846 us; speedup vs baseline: 1.6525x; 1.0711x over previous
//
#include <hip/hip_runtime.h>
#include <hip/hip_bf16.h>
#include <cstdint>

#define B_DIM 8192
#define D_DIM 512
#define BM 128
#define BN 128
#define BK 32
#define KSTEPS (D_DIM / BK)   // 16

typedef __attribute__((ext_vector_type(8))) short bf16x8;
typedef __attribute__((ext_vector_type(4))) float f32x4;

typedef __attribute__((address_space(1))) const void* gas_ptr;
typedef __attribute__((address_space(3))) void* las_ptr;

static __device__ __forceinline__ unsigned short f2bf(float x) {
    __hip_bfloat16 h = __float2bfloat16(x);
    return *reinterpret_cast<unsigned short*>(&h);
}

// One wave per row: L2-normalize (f32) and emit bf16.
__global__ __launch_bounds__(256) void normalize_rows(
    const float* __restrict__ V, const float* __restrict__ T,
    unsigned short* __restrict__ Vn, unsigned short* __restrict__ Tn)
{
    const int wave = threadIdx.x >> 6;
    const int lane = threadIdx.x & 63;
    const int row = blockIdx.x * 4 + wave;     // 0..16383 (V rows then T rows)
    const float* src;
    unsigned short* dst;
    if (row < B_DIM) {
        src = V + (size_t)row * D_DIM;
        dst = Vn + (size_t)row * D_DIM;
    } else {
        src = T + (size_t)(row - B_DIM) * D_DIM;
        dst = Tn + (size_t)(row - B_DIM) * D_DIM;
    }
    float4 a = *(const float4*)(src + lane * 4);
    float4 b = *(const float4*)(src + 256 + lane * 4);
    float ss = a.x*a.x + a.y*a.y + a.z*a.z + a.w*a.w
             + b.x*b.x + b.y*b.y + b.z*b.z + b.w*b.w;
    #pragma unroll
    for (int off = 32; off; off >>= 1) ss += __shfl_xor(ss, off);
    const float inv = 1.0f / fmaxf(sqrtf(ss), 1e-12f);
    ushort4 oa, ob;
    oa.x = f2bf(a.x * inv); oa.y = f2bf(a.y * inv);
    oa.z = f2bf(a.z * inv); oa.w = f2bf(a.w * inv);
    ob.x = f2bf(b.x * inv); ob.y = f2bf(b.y * inv);
    ob.z = f2bf(b.z * inv); ob.w = f2bf(b.w * inv);
    *(ushort4*)(dst + lane * 4) = oa;
    *(ushort4*)(dst + 256 + lane * 4) = ob;
}

// mask[i][j] = noisy[i] | noisy[j] : only two row images exist.
// Pure linear stream: per wave-instruction 64 lanes x 16B = 1KB contiguous.
__global__ __launch_bounds__(256) void mask_fill(
    const int* __restrict__ noisy, float* __restrict__ mask_out)
{
    const int t = threadIdx.x;
    f32x4 ones;
    ones[0] = ones[1] = ones[2] = ones[3] = 1.0f;
    f32x4 pat[8];
    #pragma unroll
    for (int q = 0; q < 8; ++q) {
        const int4 nz = *(const int4*)&noisy[q * 1024 + t * 4];
        pat[q][0] = nz.x ? 1.0f : 0.0f;
        pat[q][1] = nz.y ? 1.0f : 0.0f;
        pat[q][2] = nz.z ? 1.0f : 0.0f;
        pat[q][3] = nz.w ? 1.0f : 0.0f;
    }
    const int row0 = blockIdx.x * 4;
    for (int r = 0; r < 4; ++r) {
        const int row = row0 + r;
        const int rn = noisy[row];          // uniform per block-row
        float* dst = mask_out + (size_t)row * B_DIM;
        if (rn) {
            #pragma unroll
            for (int q = 0; q < 8; ++q)
                *(f32x4*)(dst + q * 1024 + t * 4) = ones;
        } else {
            #pragma unroll
            for (int q = 0; q < 8; ++q)
                *(f32x4*)(dst + q * 1024 + t * 4) = pat[q];
        }
    }
}

// R6 K-loop (double-buffered, 4096 blocks, XCD-band mapping) + epilogue that
// restages sim through LDS so each store instruction writes 2 x 512B
// contiguous row segments (instead of 16 x 64B scatter). Mask handled by
// mask_fill; rowsum via per-row atomic as in R6.
__global__ __launch_bounds__(256, 4) void gemm_fused(
    const unsigned short* __restrict__ Vn, const unsigned short* __restrict__ Tn,
    const int* __restrict__ noisy,
    float* __restrict__ sim_out, float* __restrict__ rowsum)
{
    // 32KB: staging (2x8KB A + 2x8KB B) during K-loop; f32[64][128] during epilogue
    __shared__ __align__(16) unsigned char smem[32768];
    unsigned short* Al = (unsigned short*)smem;            // [2][4096]
    unsigned short* Bl = (unsigned short*)(smem + 16384);  // [2][4096]

    const int tid  = threadIdx.x;
    const int wave = tid >> 6;
    const int lane = tid & 63;
    const int wr = wave >> 1;       // wave row (0..1)
    const int wc = wave & 1;        // wave col (0..1)

    // XCD-band mapping: xcd = bid&7 owns row band [xcd*8, xcd*8+8) panels;
    // column-panel-major within the band (proven FETCH win, R5: 77MB).
    const int bid = blockIdx.x;
    const int xcd = bid & 7;
    const int i   = bid >> 3;          // 0..511
    const int cp  = i >> 3;            // col panel 0..63 (slow)
    const int rp  = i & 7;             // row panel within band (fast)
    const int brow = (xcd * 8 + rp) * BM;
    const int bcol = cp * BN;

    const int sr = lane >> 2;          // staging row within 16-row chunk
    const int sc = (lane & 3) * 8;     // staging col (bf16 elements)
    const int c0 = wave * 2;

    const int fr = lane & 15;
    const int ko = (lane >> 4) * 8;

#define STAGE(buf, k0) do {                                                        \
        _Pragma("unroll")                                                          \
        for (int q = 0; q < 2; ++q) {                                              \
            const int cw  = c0 + q;                                                \
            const int row = cw * 16 + sr;                                          \
            const unsigned short* ga = Vn + (size_t)(brow + row) * D_DIM + (k0) + sc; \
            const unsigned short* gb = Tn + (size_t)(bcol + row) * D_DIM + (k0) + sc; \
            __builtin_amdgcn_global_load_lds((gas_ptr)ga, (las_ptr)&Al[(buf) * 4096 + cw * 512], 16, 0, 0); \
            __builtin_amdgcn_global_load_lds((gas_ptr)gb, (las_ptr)&Bl[(buf) * 4096 + cw * 512], 16, 0, 0); \
        }                                                                          \
    } while (0)

    f32x4 acc[4][4] = {};              // sim^T fragments

    STAGE(0, 0);
    __syncthreads();

    for (int t = 0; t < KSTEPS; ++t) {
        const int cur = t & 1;
        if (t < KSTEPS - 1)
            STAGE(cur ^ 1, (t + 1) * BK);   // prefetch next tile

        bf16x8 af[4], bfr[4];
        #pragma unroll
        for (int m = 0; m < 4; ++m)
            af[m] = *(const bf16x8*)&Al[cur * 4096 + (wr * 64 + m * 16 + fr) * BK + ko];
        #pragma unroll
        for (int n = 0; n < 4; ++n)
            bfr[n] = *(const bf16x8*)&Bl[cur * 4096 + (wc * 64 + n * 16 + fr) * BK + ko];

        // swapped operands: lane holds sim[m*16+(lane&15)][n*16+(lane>>4)*4+r]
        #pragma unroll
        for (int m = 0; m < 4; ++m)
            #pragma unroll
            for (int n = 0; n < 4; ++n)
                acc[m][n] = __builtin_amdgcn_mfma_f32_16x16x32_bf16(
                    bfr[n], af[m], acc[m][n], 0, 0, 0);

        __syncthreads();
    }
#undef STAGE

    const float Tinv = 1.0f / 0.07f;
    const int ci = lane & 15;           // sim row within 16-block
    const int cg = lane >> 4;           // sim col group (4 cols each)

    // ---- rowsum (from acc registers; mask not materialized here) ----
    int rn[4];
    #pragma unroll
    for (int m = 0; m < 4; ++m)
        rn[m] = noisy[brow + wr * 64 + m * 16 + ci];
    int4 cn4[4];
    #pragma unroll
    for (int n = 0; n < 4; ++n)
        cn4[n] = *(const int4*)&noisy[bcol + wc * 64 + n * 16 + cg * 4];

    #pragma unroll
    for (int m = 0; m < 4; ++m) {
        const int grow = brow + wr * 64 + m * 16 + ci;
        float partial = 0.0f;
        #pragma unroll
        for (int n = 0; n < 4; ++n) {
            const f32x4 s = acc[m][n];
            partial += (rn[m] | cn4[n].x) ? __expf(s[0] * Tinv) : 0.0f;
            partial += (rn[m] | cn4[n].y) ? __expf(s[1] * Tinv) : 0.0f;
            partial += (rn[m] | cn4[n].z) ? __expf(s[2] * Tinv) : 0.0f;
            partial += (rn[m] | cn4[n].w) ? __expf(s[3] * Tinv) : 0.0f;
        }
        partial += __shfl_xor(partial, 16);
        partial += __shfl_xor(partial, 32);
        if (lane < 16) atomicAdd(&rowsum[grow], partial);
    }

    // ---- sim stores: restage through LDS for row-contiguous segments ----
    // fbuf = f32[64][128], swizzle byte ^= (row&7)<<6 (2-way max both sides).
    const int l31  = tid & 31;
    const int rsub = tid >> 5;          // 0..7
    for (int h = 0; h < 2; ++h) {
        __syncthreads();                // fbuf free (staging reads / prev phase done)
        if (wr == h) {
            #pragma unroll
            for (int m = 0; m < 4; ++m) {
                const int row = m * 16 + ci;            // 0..63
                #pragma unroll
                for (int n = 0; n < 4; ++n) {
                    const int col = wc * 64 + n * 16 + cg * 4;
                    int byte = (row * 128 + col) * 4;
                    byte ^= (row & 7) << 6;
                    *(f32x4*)(smem + byte) = acc[m][n];
                }
            }
        }
        __syncthreads();
        #pragma unroll
        for (int j = 0; j < 8; ++j) {
            const int row = j * 8 + rsub;               // 0..63
            int byte = (row * 128 + l31 * 4) * 4;
            byte ^= (row & 7) << 6;
            const f32x4 v = *(const f32x4*)(smem + byte);
            const int grow = brow + h * 64 + row;
            *(f32x4*)(sim_out + (size_t)grow * B_DIM + bcol + l31 * 4) = v;
        }
    }
}

__global__ __launch_bounds__(256) void loss_reduce(
    const float* __restrict__ rowsum, float* __restrict__ out)
{
    __shared__ float wsum[4];
    float s = 0.0f;
    for (int i = threadIdx.x; i < B_DIM; i += 256)
        s += logf(rowsum[i] + 1e-8f);
    #pragma unroll
    for (int off = 32; off; off >>= 1) s += __shfl_xor(s, off);
    if ((threadIdx.x & 63) == 0) wsum[threadIdx.x >> 6] = s;
    __syncthreads();
    if (threadIdx.x == 0) {
        const float t = (wsum[0] + wsum[1]) + (wsum[2] + wsum[3]);
        const float loss = t * (1.0f / (float)B_DIM);
        out[0] = loss;   // complementary_loss
        out[1] = loss;   // brownian_loss (identical chain)
    }
}

extern "C" void kernel_launch(void* const* d_in, const int* in_sizes, int n_in,
                              void* d_out, int out_size, void* d_ws, size_t ws_size,
                              hipStream_t stream) {
    const float* V = (const float*)d_in[0];
    const float* T = (const float*)d_in[1];
    const int* noisy = (const int*)d_in[3];   // confident_clean_mask (d_in[2]) unused
    float* out = (float*)d_out;

    float* mask_out = out + 2;
    float* sim_out  = out + 2 + (size_t)B_DIM * B_DIM;

    unsigned short* Vn = (unsigned short*)d_ws;                       // 8 MB
    unsigned short* Tn = Vn + (size_t)B_DIM * D_DIM;                  // 8 MB
    float* rowsum = (float*)(Tn + (size_t)B_DIM * D_DIM);             // 32 KB

    hipMemsetAsync(rowsum, 0, B_DIM * sizeof(float), stream);
    normalize_rows<<<(2 * B_DIM) / 4, 256, 0, stream>>>(V, T, Vn, Tn);
    mask_fill<<<B_DIM / 4, 256, 0, stream>>>(noisy, mask_out);
    gemm_fused<<<64 * 64, 256, 0, stream>>>(Vn, Tn, noisy, sim_out, rowsum);
    loss_reduce<<<1, 256, 0, stream>>>(rowsum, out);
}